// Round 8
// baseline (385.522 us; speedup 1.0000x reference)
//
#include <hip/hip_runtime.h>

// Problem constants: B=32, T=1024, IN=1024, OUT=1024
// M = B*T = 32768, K = IN = 1024, N = OUT = 1024
#define M_DIM 32768
#define N_DIM 1024
#define K_DIM 1024
#define T_DIM 1024
#define B_DIM 32
#define TSUB 128          // timesteps per m-subtile
#define NSUB (T_DIM / TSUB)   // 8

typedef unsigned int uint32;
typedef __attribute__((ext_vector_type(8))) short short8;       // 8 bf16 (MFMA A/B frag)
typedef __attribute__((ext_vector_type(8))) unsigned short ushort8v;
typedef __attribute__((ext_vector_type(4))) float floatx4;      // MFMA C/D frag

__device__ __forceinline__ unsigned short f2bf(float f) {
    uint32 u = __float_as_uint(f);
    uint32 r = u + 0x7fffu + ((u >> 16) & 1u);
    return (unsigned short)(r >> 16);
}

__device__ __forceinline__ void async_load16(const void* g, void* s) {
    __builtin_amdgcn_global_load_lds(
        (const __attribute__((address_space(1))) void*)g,
        (__attribute__((address_space(3))) void*)s,
        16, 0, 0);
}

// ---------------------------------------------------------------------------
// Fused fp32 -> bf16 cast for A and W in one dispatch (R1/R4-verified).
// ---------------------------------------------------------------------------
__global__ void cast_f32_bf16_fused(const float* __restrict__ X,
                                    const float* __restrict__ Wt,
                                    unsigned short* __restrict__ dst,
                                    int nA8, int nTot8) {
    int i = blockIdx.x * blockDim.x + threadIdx.x;
    if (i < nTot8) {
        const float* src = (i < nA8) ? (X + (size_t)i * 8)
                                     : (Wt + (size_t)(i - nA8) * 8);
        float4 v0 = ((const float4*)src)[0];
        float4 v1 = ((const float4*)src)[1];
        ushort8v o;
        o[0] = f2bf(v0.x); o[1] = f2bf(v0.y); o[2] = f2bf(v0.z); o[3] = f2bf(v0.w);
        o[4] = f2bf(v1.x); o[5] = f2bf(v1.y); o[6] = f2bf(v1.z); o[7] = f2bf(v1.w);
        ((ushort8v*)dst)[i] = o;
    }
}

// ---------------------------------------------------------------------------
// FULLY-FUSED GEMM + leaky-integrator scan, v2: IN-REGISTER scan.
// One block = (batch, 64-col slice): grid 512 = 2 resident blocks/CU (true
// GEMM/scan overlap across blocks). Per subtile (128 t):
//   1. 128x64 BK=64 double-buffered MFMA GEMM (R4-verified schedule),
//      8 waves = 2 row-halves x 4 col-quarters, acc[4] (4 frags x 4 regs).
//   2. Weighted prefix scan DIRECTLY on acc (no LDS tile, no conflicts):
//      in-lane 4-row chains -> Kogge-Stone over quads (shfl_up 16/32,
//      weight a^4) -> a^16-chained fragment carries; all affine in u_in:
//      out_t = H_local[t] + a^(t+1) * u_in.
//   3. Tiny LDS handoff: Hs[2][64] (half sums), UcarB[2][64] (subtile
//      carry, parity double-buffered). Coalesced fp32 out stores.
// LDS 49 KB (A 2x16K, B 2x8K, handoff 1K). A-reuse (16 blocks/batch) is
// L3-absorbed (all 512 blocks co-resident).
// ---------------------------------------------------------------------------
#define STAGE_A(db, rbase, k0)                                            \
  { _Pragma("unroll")                                                     \
    for (int q = 0; q < 2; ++q) {                                         \
      int slot = q * 512 + tid;                                           \
      int row  = slot >> 3;                                               \
      int ch   = slot & 7;                                                \
      int sc   = ch ^ (row & 7);                                          \
      async_load16(Ag + (size_t)((rbase) + row) * K_DIM + (k0) + sc * 8,  \
                   &As[db][slot * 8]);                                    \
    } }

#define STAGE_B(db, k0)                                                   \
  { int row = tid >> 3;                                                   \
    int ch  = tid & 7;                                                    \
    int sc  = ch ^ (row & 7);                                             \
    async_load16(Bg + (size_t)(bn0 + row) * K_DIM + (k0) + sc * 8,        \
                 &Bs[db][tid * 8]); }

#define COMPUTE(db)                                                       \
  { _Pragma("unroll")                                                     \
    for (int ks = 0; ks < 2; ++ks) {                                      \
      short8 af[4], bfr;                                                  \
      _Pragma("unroll")                                                   \
      for (int m = 0; m < 4; ++m) {                                       \
        int r = wm * 64 + m * 16 + l15;                                   \
        int c = ks * 4 + quad;                                            \
        af[m] = *(const short8*)&As[db][r * 64 + ((c ^ (r & 7)) * 8)];    \
      }                                                                   \
      { int rb = wn * 16 + l15;                                           \
        int c  = ks * 4 + quad;                                           \
        bfr = *(const short8*)&Bs[db][rb * 64 + ((c ^ (rb & 7)) * 8)]; }  \
      _Pragma("unroll")                                                   \
      for (int m = 0; m < 4; ++m)                                         \
        acc[m] = __builtin_amdgcn_mfma_f32_16x16x32_bf16(                 \
            af[m], bfr, acc[m], 0, 0, 0);                                 \
    } }

__global__ __launch_bounds__(512) void gemm_scan_reg(
    const unsigned short* __restrict__ Ag,  // [M, K] bf16
    const unsigned short* __restrict__ Bg,  // [N, K] bf16
    const float* __restrict__ bias,         // [N]
    const float* __restrict__ decay,        // [N]
    float* __restrict__ out) {              // [M, N] fp32
    __shared__ unsigned short As[2][128 * 64];   // 2 x 16 KB
    __shared__ unsigned short Bs[2][64 * 64];    // 2 x 8 KB
    __shared__ float Hs[2][64];                  // per-half 64-row sums
    __shared__ float UcarB[2][64];               // subtile carry (parity)

    const int tid  = threadIdx.x;            // 0..511
    const int lane = tid & 63;
    const int l15  = lane & 15;
    const int quad = lane >> 4;
    const int wid  = tid >> 6;               // 0..7
    const int wm   = wid >> 2;               // 0..1 (64-row half)
    const int wn   = wid & 3;                // 0..3 (16-col quarter)

    // Block map: 512 blocks; xcd hosts 4 batches x 16 col-slices.
    const int L     = blockIdx.x;
    const int xcd   = L & 7;
    const int v     = L >> 3;                // 0..63
    const int batch = xcd * 4 + (v >> 4);
    const int bn0   = (v & 15) * 64;

    // Per-lane column constants (hoisted; loop-invariant).
    const int cl = wn * 16 + l15;            // col within slice [0,64)
    const float a   = decay[bn0 + cl];
    const float cc  = 1.0f - a;
    const float bb  = bias[bn0 + cl];
    const float a2  = a * a;
    const float a3  = a2 * a;
    const float a4  = a2 * a2;
    const float a8  = a4 * a4;
    const float a16 = a8 * a8;
    const float a32 = a16 * a16;
    const float a64 = a32 * a32;
    float aq = a;                            // a^(quad*4+1)
    if (quad & 1) aq *= a4;
    if (quad & 2) aq *= a8;
    const float ap0 = aq, ap1 = aq * a, ap2 = ap1 * a, ap3 = ap2 * a;

    if (tid < 64) UcarB[0][tid] = 0.f;

    floatx4 acc[4];

    // Initial stage: subtile 0, k-tile 0 into buf 0.
    STAGE_A(0, batch * T_DIM, 0);
    STAGE_B(0, 0);

#pragma unroll 1
    for (int s = 0; s < NSUB; ++s) {
        const int rbase = batch * T_DIM + s * TSUB;
#pragma unroll
        for (int m = 0; m < 4; ++m)
            acc[m] = (floatx4){0.f, 0.f, 0.f, 0.f};

        __syncthreads();   // buf0 staging complete (barrier drains vmcnt)

        // ---- R4-verified double-buffered K loop ----
#pragma unroll 1
        for (int kt = 0; kt < 16; kt += 2) {
            STAGE_A(1, rbase, (kt + 1) * 64);
            STAGE_B(1, (kt + 1) * 64);
            COMPUTE(0);
            __syncthreads();
            if (kt + 2 < 16) {
                STAGE_A(0, rbase, (kt + 2) * 64);
                STAGE_B(0, (kt + 2) * 64);
            }
            COMPUTE(1);
            __syncthreads();
        }

        // Prefetch next subtile's k-tile 0 (drains at the Hs barrier below,
        // hidden under the scan VALU work).
        if (s + 1 < NSUB) {
            STAGE_A(0, rbase + TSUB, 0);
            STAGE_B(0, 0);
        }

        // ---- in-register hierarchical scan over the 64 rows (this half) --
        // Local zero-init prefixes H[m][r]; all-affine in the carry-in.
        float H[4][4];
        float carry = 0.f;                   // a^16-chained fragment carry
#pragma unroll
        for (int m = 0; m < 4; ++m) {
            float p0 = cc * (acc[m][0] + bb);
            float p1 = a * p0 + cc * (acc[m][1] + bb);
            float p2 = a * p1 + cc * (acc[m][2] + bb);
            float p3 = a * p2 + cc * (acc[m][3] + bb);
            // Kogge-Stone inclusive prefix of 4-row sums across quads (w=a^4)
            float S  = p3;
            float g1 = __shfl_up(S, 16);
            float z  = S + a4 * ((quad >= 1) ? g1 : 0.f);
            float g2 = __shfl_up(z, 32);
            float Z  = z + a8 * ((quad >= 2) ? g2 : 0.f);
            float gE = __shfl_up(Z, 16);
            float E  = (quad >= 1) ? gE : 0.f;   // carry into my 4 rows
            float P0 = p0 + a  * E;
            float P1 = p1 + a2 * E;
            float P2 = p2 + a3 * E;
            float P3 = p3 + a4 * E;
            H[m][0] = P0 + ap0 * carry;
            H[m][1] = P1 + ap1 * carry;
            H[m][2] = P2 + ap2 * carry;
            H[m][3] = P3 + ap3 * carry;
            float Ff = __shfl(Z, 48 + l15);      // fragment-final (quad 3)
            carry = a16 * carry + Ff;
        }
        // carry = zero-init state after this half's 64 rows
        if (quad == 0) Hs[wm][cl] = carry;
        __syncthreads();                         // Hs visible + vmcnt drained

        float Uc  = UcarB[s & 1][cl];
        float uin = (wm == 0) ? Uc : (a64 * Uc + Hs[0][cl]);

        float wmu = uin;
        size_t ob = (size_t)(rbase + wm * 64 + quad * 4) * N_DIM + bn0 + cl;
#pragma unroll
        for (int m = 0; m < 4; ++m) {
            out[ob + (size_t)(m * 16 + 0) * N_DIM] = H[m][0] + ap0 * wmu;
            out[ob + (size_t)(m * 16 + 1) * N_DIM] = H[m][1] + ap1 * wmu;
            out[ob + (size_t)(m * 16 + 2) * N_DIM] = H[m][2] + ap2 * wmu;
            out[ob + (size_t)(m * 16 + 3) * N_DIM] = H[m][3] + ap3 * wmu;
            wmu *= a16;
        }
        if (wm == 1 && quad == 0)
            UcarB[(s + 1) & 1][cl] = a64 * uin + carry;
        // loop-top __syncthreads() orders UcarB write vs next subtile reads
    }
}

// ---------------------------------------------------------------------------
// Fallbacks (only used if workspace too small for the bf16 path)
// ---------------------------------------------------------------------------
__global__ void scan_f32_inplace(float* __restrict__ buf,
                                 const float* __restrict__ decay) {
    int tid = blockIdx.x * 64 + threadIdx.x;
    int o = tid & (N_DIM - 1);
    size_t base = ((size_t)(tid >> 10) << 20) + o;
    float a = decay[o];
    float c = 1.f - a;
    float u = 0.f;
    for (int t0 = 0; t0 < 1024; t0 += 16) {
        float x[16];
#pragma unroll
        for (int k = 0; k < 16; ++k)
            x[k] = buf[base + (size_t)(t0 + k) * N_DIM];
#pragma unroll
        for (int k = 0; k < 16; ++k) {
            u = a * u + c * x[k];
            buf[base + (size_t)(t0 + k) * N_DIM] = u;
        }
    }
}

__global__ void gemm_naive(const float* __restrict__ X, const float* __restrict__ W,
                           const float* __restrict__ bias, float* __restrict__ out) {
    __shared__ float As[16][17], Bs[16][17];
    int tx = threadIdx.x, ty = threadIdx.y;
    int m0 = blockIdx.y * 16, n0 = blockIdx.x * 16;
    float acc = 0.f;
    for (int k0 = 0; k0 < K_DIM; k0 += 16) {
        As[ty][tx] = X[(size_t)(m0 + ty) * K_DIM + k0 + tx];
        Bs[ty][tx] = W[(size_t)(n0 + ty) * K_DIM + k0 + tx];
        __syncthreads();
#pragma unroll
        for (int kk = 0; kk < 16; ++kk) acc += As[ty][kk] * Bs[tx][kk];
        __syncthreads();
    }
    out[(size_t)(m0 + ty) * N_DIM + n0 + tx] = acc + bias[n0 + tx];
}

// ---------------------------------------------------------------------------
extern "C" void kernel_launch(void* const* d_in, const int* in_sizes, int n_in,
                              void* d_out, int out_size, void* d_ws, size_t ws_size,
                              hipStream_t stream) {
    const float* X     = (const float*)d_in[0];  // [B,T,IN]  = [M,K]
    const float* Wt    = (const float*)d_in[1];  // [OUT,IN]  = [N,K]
    const float* bias  = (const float*)d_in[2];  // [OUT]
    const float* decay = (const float*)d_in[3];  // [OUT]
    float* out = (float*)d_out;                  // [B,T,OUT] = [M,N]

    const size_t A_bytes = (size_t)M_DIM * K_DIM * 2;            // 64 MB
    const size_t W_bytes = (size_t)N_DIM * K_DIM * 2;            // 2 MB
    const size_t need    = A_bytes + W_bytes;                    // 66 MB

    const int nA8   = M_DIM * K_DIM / 8;
    const int nW8   = N_DIM * K_DIM / 8;
    const int nTot8 = nA8 + nW8;

    if (ws_size >= need) {
        unsigned short* Abf = (unsigned short*)d_ws;
        unsigned short* Wbf = (unsigned short*)((char*)d_ws + A_bytes);
        cast_f32_bf16_fused<<<(nTot8 + 255) / 256, 256, 0, stream>>>(X, Wt, Abf, nA8, nTot8);
        gemm_scan_reg<<<B_DIM * (N_DIM / 64), 512, 0, stream>>>(
            Abf, Wbf, bias, decay, out);
    } else {
        gemm_naive<<<dim3(N_DIM / 16, M_DIM / 16), dim3(16, 16), 0, stream>>>(X, Wt, bias, out);
        scan_f32_inplace<<<512, 64, 0, stream>>>(out, decay);
    }
}

// Round 9
// 349.394 us; speedup vs baseline: 1.1034x; 1.1034x over previous
//
#include <hip/hip_runtime.h>

// Problem constants: B=32, T=1024, IN=1024, OUT=1024
// M = B*T = 32768, K = IN = 1024, N = OUT = 1024
#define M_DIM 32768
#define N_DIM 1024
#define K_DIM 1024
#define T_DIM 1024
#define B_DIM 32
#define NCHUNK 16
#define CHUNK_T 64    // T_DIM / NCHUNK; one chunk per GEMM wave-half (wm)

typedef unsigned int uint32;
typedef __attribute__((ext_vector_type(8))) short short8;       // 8 bf16 (MFMA A/B frag)
typedef __attribute__((ext_vector_type(8))) unsigned short ushort8v;
typedef __attribute__((ext_vector_type(4))) unsigned short ushort4v;
typedef __attribute__((ext_vector_type(4))) float floatx4;      // MFMA C/D frag

__device__ __forceinline__ unsigned short f2bf(float f) {
    uint32 u = __float_as_uint(f);
    uint32 r = u + 0x7fffu + ((u >> 16) & 1u);
    return (unsigned short)(r >> 16);
}

__device__ __forceinline__ void async_load16(const void* g, void* s) {
    __builtin_amdgcn_global_load_lds(
        (const __attribute__((address_space(1))) void*)g,
        (__attribute__((address_space(3))) void*)s,
        16, 0, 0);
}

// ---------------------------------------------------------------------------
// fp32 -> bf16 cast v2: fully-coalesced loads. Block-level source select
// (blocks [0,8192) -> A, [8192,8448) -> W). 16 floats/thread: 4 float4
// loads, each instruction wave-contiguous (64 lanes x 16B = 1KB), hoisted
// ahead of 4 x 8B ushort4 stores (wave-contiguous, 8B/lane). Replaces the
// stride-2 load pattern measured at 4.2 TB/s (46 us); target ~33 us.
// ---------------------------------------------------------------------------
__global__ __launch_bounds__(256) void cast_f32_bf16_v2(
    const float* __restrict__ X,            // [M*K] fp32
    const float* __restrict__ Wt,           // [N*K] fp32
    unsigned short* __restrict__ Abf,       // [M*K] bf16
    unsigned short* __restrict__ Wbf,       // [N*K] bf16
    int nAblocks) {                         // = M*K/4096
    const int b = blockIdx.x;
    const int t = threadIdx.x;
    const float4* s4;
    ushort4v*     d4;
    int base;
    if (b < nAblocks) {
        s4 = (const float4*)X;  d4 = (ushort4v*)Abf;  base = b * 1024;
    } else {
        s4 = (const float4*)Wt; d4 = (ushort4v*)Wbf;  base = (b - nAblocks) * 1024;
    }
    float4 v[4];
#pragma unroll
    for (int q = 0; q < 4; ++q)
        v[q] = s4[base + q * 256 + t];
#pragma unroll
    for (int q = 0; q < 4; ++q) {
        ushort4v o;
        o[0] = f2bf(v[q].x); o[1] = f2bf(v[q].y);
        o[2] = f2bf(v[q].z); o[3] = f2bf(v[q].w);
        d4[base + q * 256 + t] = o;
    }
}

// ---------------------------------------------------------------------------
// bf16 MFMA GEMM, DOUBLE-BUFFERED (R4-verified, 96.7 us / 710 TF): next
// k-tile's global_load_lds issues BEFORE the current tile's ds_read+MFMA,
// one __syncthreads() per k-tile. Two named buffer pairs. 128x128 tile,
// BK=64, 4 waves, XCD-aware remap, fused chunk-carry epilogue.
// ---------------------------------------------------------------------------
#define STAGE_TILE(AsD, BsD, k0)                                          \
  {                                                                       \
    _Pragma("unroll")                                                     \
    for (int q = 0; q < 4; ++q) {                                         \
      int slot = q * 256 + tid;                                           \
      int row  = slot >> 3;                                               \
      int ch   = slot & 7;                                                \
      int sc   = ch ^ (row & 7);                                          \
      async_load16(Ag + (size_t)(bm0 + row) * K_DIM + (k0) + sc * 8,      \
                   &AsD[(q * 256 + wid * 64) * 8]);                       \
    }                                                                     \
    _Pragma("unroll")                                                     \
    for (int q = 0; q < 4; ++q) {                                         \
      int slot = q * 256 + tid;                                           \
      int row  = slot >> 3;                                               \
      int ch   = slot & 7;                                                \
      int sc   = ch ^ (row & 7);                                          \
      async_load16(Bg + (size_t)(bn0 + row) * K_DIM + (k0) + sc * 8,      \
                   &BsD[(q * 256 + wid * 64) * 8]);                       \
    }                                                                     \
  }

#define COMPUTE_TILE(AsS, BsS)                                            \
  {                                                                       \
    _Pragma("unroll")                                                     \
    for (int ks = 0; ks < 2; ++ks) {                                      \
      short8 af[4], bfr[4];                                               \
      _Pragma("unroll")                                                   \
      for (int i = 0; i < 4; ++i) {                                       \
        int r = wm * 64 + i * 16 + l15;                                   \
        int c = ks * 4 + quad;                                            \
        af[i] = *(const short8*)&AsS[r * 64 + ((c ^ (r & 7)) * 8)];       \
      }                                                                   \
      _Pragma("unroll")                                                   \
      for (int j = 0; j < 4; ++j) {                                       \
        int r = wn * 64 + j * 16 + l15;                                   \
        int c = ks * 4 + quad;                                            \
        bfr[j] = *(const short8*)&BsS[r * 64 + ((c ^ (r & 7)) * 8)];      \
      }                                                                   \
      _Pragma("unroll")                                                   \
      for (int i = 0; i < 4; ++i)                                         \
        _Pragma("unroll")                                                 \
        for (int j = 0; j < 4; ++j)                                       \
          acc[i][j] = __builtin_amdgcn_mfma_f32_16x16x32_bf16(            \
              af[i], bfr[j], acc[i][j], 0, 0, 0);                         \
    }                                                                     \
  }

__global__ __launch_bounds__(256) void gemm_mfma_db(
    const unsigned short* __restrict__ Ag,  // [M, K] bf16
    const unsigned short* __restrict__ Bg,  // [N, K] bf16
    const float* __restrict__ bias,         // [N]
    const float* __restrict__ decay,        // [N]
    unsigned short* outBf,                  // [M, N] bf16 (or null)
    float* outF,                            // [M, N] fp32 (or null)
    float* carry) {                         // [B, NCHUNK, N] (or null)
    __shared__ unsigned short As0[128 * 64];
    __shared__ unsigned short Bs0[128 * 64];
    __shared__ unsigned short As1[128 * 64];
    __shared__ unsigned short Bs1[128 * 64];

    const int tid  = threadIdx.x;
    const int lane = tid & 63;
    const int wid  = tid >> 6;
    const int l15  = lane & 15;
    const int quad = lane >> 4;
    const int wm   = wid >> 1;
    const int wn   = wid & 1;

    // XCD-aware remap (grid is (8, 256) -> L in [0, 2048))
    const int L    = blockIdx.y * gridDim.x + blockIdx.x;
    const int xcd  = L & 7;
    const int s    = L >> 3;
    const int bn0  = (s & 7) * 128;                 // N-tile
    const int bm0  = (xcd * 32 + (s >> 3)) * 128;   // M-panel

    floatx4 acc[4][4];
#pragma unroll
    for (int i = 0; i < 4; ++i)
#pragma unroll
        for (int j = 0; j < 4; ++j)
            acc[i][j] = (floatx4){0.f, 0.f, 0.f, 0.f};

    // Prologue: stage tile 0 into buffer 0.
    STAGE_TILE(As0, Bs0, 0);
    __syncthreads();

    // 16 k-tiles, processed 2 per unrolled iteration (ping/pong).
#pragma unroll 1
    for (int kt = 0; kt < K_DIM / 64; kt += 2) {
        STAGE_TILE(As1, Bs1, (kt + 1) * 64);    // in flight during compute
        COMPUTE_TILE(As0, Bs0);
        __syncthreads();                        // drains vmcnt + syncs buf0 reuse
        if (kt + 2 < K_DIM / 64)
            STAGE_TILE(As0, Bs0, (kt + 2) * 64);
        COMPUTE_TILE(As1, Bs1);
        __syncthreads();
    }

    // C/D layout: col = lane&15, row = quad*4 + reg
#pragma unroll
    for (int j = 0; j < 4; ++j) {
        int col = bn0 + wn * 64 + j * 16 + l15;
        float bb = bias[col];
#pragma unroll
        for (int i = 0; i < 4; ++i) {
            int rowb = bm0 + wm * 64 + i * 16 + quad * 4;
#pragma unroll
            for (int r = 0; r < 4; ++r) {
                float v = acc[i][j][r] + bb;
                size_t idx = (size_t)(rowb + r) * N_DIM + col;
                if (outBf) outBf[idx] = f2bf(v);
                else       outF[idx]  = v;
            }
        }
    }

    // ---- fused chunk-carry epilogue (harness-verified R1/R4) ----
    // U = (1-a)*sum_{rloc} a^(63-rloc)*acc + bias*(1-a^64), rloc = i*16+quad*4+r
    if (carry) {
        const int bIdx = bm0 >> 10;                       // / T_DIM
        const int g    = ((bm0 & (T_DIM - 1)) >> 6) + wm; // chunk index
#pragma unroll
        for (int j = 0; j < 4; ++j) {
            int col = bn0 + wn * 64 + j * 16 + l15;
            float a   = decay[col];
            float bb  = bias[col];
            float a2  = a * a;
            float a4  = a2 * a2;
            float a8  = a4 * a4;
            float a12 = a8 * a4;
            float a64 = a12 * a4;          // a^16
            a64 = a64 * a64;               // a^32
            a64 = a64 * a64;               // a^64
            float w = (quad == 0) ? a12 : (quad == 1) ? a8
                    : (quad == 2) ? a4  : 1.0f;
            float sacc = 0.f;
#pragma unroll
            for (int i = 3; i >= 0; --i) {
#pragma unroll
                for (int r = 3; r >= 0; --r) {
                    sacc += w * acc[i][j][r];
                    w *= a;
                }
                if (i) w *= a12;           // row gap 13 across fragments
            }
            sacc += __shfl_xor(sacc, 16);
            sacc += __shfl_xor(sacc, 32);
            float U = (1.0f - a) * sacc + bb * (1.0f - a64);
            if (quad == 0)
                carry[((size_t)bIdx * NCHUNK + g) * N_DIM + col] = U;
        }
    }
}

// ---------------------------------------------------------------------------
// Apply pass, 4-wide over o: uint2 loads (8B/lane), float4 stores (16B/lane).
// Thread <-> (b, chunk, o4): o4 = tid&255, chunk = (tid>>8)&15, b = tid>>12.
// 131072 threads = 2048 waves = 8 waves/CU; 32-deep load pipeline.
// ---------------------------------------------------------------------------
__global__ __launch_bounds__(256) void scan_apply4(
    const uint2* __restrict__ cur4,           // [M, N/4] (2x bf16-pair)
    const float* __restrict__ decay,
    const float* __restrict__ carry,          // [B, NCHUNK, N]
    float* __restrict__ out) {                // [M, N] fp32
    int tid   = blockIdx.x * 256 + threadIdx.x;   // 0 .. 131071
    int o4    = tid & 255;
    int chunk = (tid >> 8) & (NCHUNK - 1);
    int b     = tid >> 12;
    int o     = o4 * 4;
    size_t base = ((size_t)b * T_DIM + (size_t)chunk * CHUNK_T) * (N_DIM / 4) + o4;
    float4 av = *(const float4*)&decay[o];
    float a0 = av.x, a1 = av.y, a2 = av.z, a3 = av.w;
    float c0 = 1.f - a0, c1 = 1.f - a1, c2 = 1.f - a2, c3 = 1.f - a3;

    float A0 = a0, A1 = a1, A2 = a2, A3 = a3;
#pragma unroll
    for (int i = 0; i < 6; ++i) { A0 *= A0; A1 *= A1; A2 *= A2; A3 *= A3; }  // a^64

    float u0 = 0.f, u1 = 0.f, u2 = 0.f, u3 = 0.f;
    const float* cb = carry + (size_t)b * NCHUNK * N_DIM + o;
    for (int i = 0; i < chunk; ++i) {         // wave-uniform trip count
        float4 cv = *(const float4*)&cb[(size_t)i * N_DIM];
        u0 = cv.x + A0 * u0;
        u1 = cv.y + A1 * u1;
        u2 = cv.z + A2 * u2;
        u3 = cv.w + A3 * u3;
    }

    float4* out4 = (float4*)out;
    for (int t0 = 0; t0 < CHUNK_T; t0 += 32) {
        uint2 x[32];
#pragma unroll
        for (int k = 0; k < 32; ++k)
            x[k] = cur4[base + (size_t)(t0 + k) * (N_DIM / 4)];
#pragma unroll
        for (int k = 0; k < 32; ++k) {
            float v0 = __uint_as_float(x[k].x << 16);
            float v1 = __uint_as_float(x[k].x & 0xffff0000u);
            float v2 = __uint_as_float(x[k].y << 16);
            float v3 = __uint_as_float(x[k].y & 0xffff0000u);
            u0 = a0 * u0 + c0 * v0;
            u1 = a1 * u1 + c1 * v1;
            u2 = a2 * u2 + c2 * v2;
            u3 = a3 * u3 + c3 * v3;
            out4[base + (size_t)(t0 + k) * (N_DIM / 4)] = (float4){u0, u1, u2, u3};
        }
    }
}

// ---------------------------------------------------------------------------
// Fallbacks (only used if workspace too small for the bf16 path)
// ---------------------------------------------------------------------------
__global__ void scan_f32_inplace(float* __restrict__ buf,
                                 const float* __restrict__ decay) {
    int tid = blockIdx.x * 64 + threadIdx.x;
    int o = tid & (N_DIM - 1);
    size_t base = ((size_t)(tid >> 10) << 20) + o;
    float a = decay[o];
    float c = 1.f - a;
    float u = 0.f;
    for (int t0 = 0; t0 < 1024; t0 += 16) {
        float x[16];
#pragma unroll
        for (int k = 0; k < 16; ++k)
            x[k] = buf[base + (size_t)(t0 + k) * N_DIM];
#pragma unroll
        for (int k = 0; k < 16; ++k) {
            u = a * u + c * x[k];
            buf[base + (size_t)(t0 + k) * N_DIM] = u;
        }
    }
}

__global__ void gemm_naive(const float* __restrict__ X, const float* __restrict__ W,
                           const float* __restrict__ bias, float* __restrict__ out) {
    __shared__ float As[16][17], Bs[16][17];
    int tx = threadIdx.x, ty = threadIdx.y;
    int m0 = blockIdx.y * 16, n0 = blockIdx.x * 16;
    float acc = 0.f;
    for (int k0 = 0; k0 < K_DIM; k0 += 16) {
        As[ty][tx] = X[(size_t)(m0 + ty) * K_DIM + k0 + tx];
        Bs[ty][tx] = W[(size_t)(n0 + ty) * K_DIM + k0 + tx];
        __syncthreads();
#pragma unroll
        for (int kk = 0; kk < 16; ++kk) acc += As[ty][kk] * Bs[tx][kk];
        __syncthreads();
    }
    out[(size_t)(m0 + ty) * N_DIM + n0 + tx] = acc + bias[n0 + tx];
}

// ---------------------------------------------------------------------------
extern "C" void kernel_launch(void* const* d_in, const int* in_sizes, int n_in,
                              void* d_out, int out_size, void* d_ws, size_t ws_size,
                              hipStream_t stream) {
    const float* X     = (const float*)d_in[0];  // [B,T,IN]  = [M,K]
    const float* Wt    = (const float*)d_in[1];  // [OUT,IN]  = [N,K]
    const float* bias  = (const float*)d_in[2];  // [OUT]
    const float* decay = (const float*)d_in[3];  // [OUT]
    float* out = (float*)d_out;                  // [B,T,OUT] = [M,N]

    const size_t A_bytes  = (size_t)M_DIM * K_DIM * 2;            // 64 MB
    const size_t W_bytes  = (size_t)N_DIM * K_DIM * 2;            // 2 MB
    const size_t C_bytes  = (size_t)M_DIM * N_DIM * 2;            // 64 MB
    const size_t cr_bytes = (size_t)B_DIM * NCHUNK * N_DIM * 4;   // 2 MB
    const size_t need_mid  = A_bytes + W_bytes;
    const size_t need_full = A_bytes + W_bytes + C_bytes + cr_bytes;

    const int nAblocks = M_DIM * K_DIM / 4096;    // 8192
    const int nWblocks = N_DIM * K_DIM / 4096;    // 256

    if (ws_size >= need_full) {
        unsigned short* Abf = (unsigned short*)d_ws;
        unsigned short* Wbf = (unsigned short*)((char*)d_ws + A_bytes);
        unsigned short* Cbf = (unsigned short*)((char*)d_ws + A_bytes + W_bytes);
        float* carry = (float*)((char*)d_ws + A_bytes + W_bytes + C_bytes);
        cast_f32_bf16_v2<<<nAblocks + nWblocks, 256, 0, stream>>>(X, Wt, Abf, Wbf, nAblocks);
        gemm_mfma_db<<<dim3(N_DIM / 128, M_DIM / 128), 256, 0, stream>>>(
            Abf, Wbf, bias, decay, Cbf, nullptr, carry);
        const int apply_threads = B_DIM * NCHUNK * N_DIM / 4;     // 131072
        scan_apply4<<<apply_threads / 256, 256, 0, stream>>>(
            (const uint2*)Cbf, decay, carry, out);
    } else if (ws_size >= need_mid) {
        unsigned short* Abf = (unsigned short*)d_ws;
        unsigned short* Wbf = (unsigned short*)((char*)d_ws + A_bytes);
        cast_f32_bf16_v2<<<nAblocks + nWblocks, 256, 0, stream>>>(X, Wt, Abf, Wbf, nAblocks);
        gemm_mfma_db<<<dim3(N_DIM / 128, M_DIM / 128), 256, 0, stream>>>(
            Abf, Wbf, bias, decay, nullptr, out, nullptr);
        scan_f32_inplace<<<512, 64, 0, stream>>>(out, decay);
    } else {
        gemm_naive<<<dim3(N_DIM / 16, M_DIM / 16), dim3(16, 16), 0, stream>>>(X, Wt, bias, out);
        scan_f32_inplace<<<512, 64, 0, stream>>>(out, decay);
    }
}

// Round 10
// 342.907 us; speedup vs baseline: 1.1243x; 1.0189x over previous
//
#include <hip/hip_runtime.h>

// Problem constants: B=32, T=1024, IN=1024, OUT=1024
// M = B*T = 32768, K = IN = 1024, N = OUT = 1024
#define M_DIM 32768
#define N_DIM 1024
#define K_DIM 1024
#define T_DIM 1024
#define B_DIM 32
#define NCHUNK 16
#define CHUNK_T 64    // T_DIM / NCHUNK; one chunk per GEMM wave-half (wm)

typedef unsigned int uint32;
typedef __attribute__((ext_vector_type(8))) short short8;       // 8 bf16 (MFMA A/B frag)
typedef __attribute__((ext_vector_type(8))) unsigned short ushort8v;
typedef __attribute__((ext_vector_type(4))) float floatx4;      // MFMA C/D frag

__device__ __forceinline__ unsigned short f2bf(float f) {
    uint32 u = __float_as_uint(f);
    uint32 r = u + 0x7fffu + ((u >> 16) & 1u);
    return (unsigned short)(r >> 16);
}

__device__ __forceinline__ void async_load16(const void* g, void* s) {
    __builtin_amdgcn_global_load_lds(
        (const __attribute__((address_space(1))) void*)g,
        (__attribute__((address_space(3))) void*)s,
        16, 0, 0);
}

// ---------------------------------------------------------------------------
// Fused fp32 -> bf16 cast for A and W in one dispatch (best measured: ~46us).
// NOTE (R9 lesson): thread i reads 32 CONTIGUOUS bytes (two adjacent
// float4), so this IS fully coalesced; and it keeps 16B/lane stores.
// The "coalesced-load/8B-store" variant (R9) measured ~10us SLOWER.
// ---------------------------------------------------------------------------
__global__ void cast_f32_bf16_fused(const float* __restrict__ X,
                                    const float* __restrict__ Wt,
                                    unsigned short* __restrict__ dst,
                                    int nA8, int nTot8) {
    int i = blockIdx.x * blockDim.x + threadIdx.x;
    if (i < nTot8) {
        const float* src = (i < nA8) ? (X + (size_t)i * 8)
                                     : (Wt + (size_t)(i - nA8) * 8);
        float4 v0 = ((const float4*)src)[0];
        float4 v1 = ((const float4*)src)[1];
        ushort8v o;
        o[0] = f2bf(v0.x); o[1] = f2bf(v0.y); o[2] = f2bf(v0.z); o[3] = f2bf(v0.w);
        o[4] = f2bf(v1.x); o[5] = f2bf(v1.y); o[6] = f2bf(v1.z); o[7] = f2bf(v1.w);
        ((ushort8v*)dst)[i] = o;
    }
}

// ---------------------------------------------------------------------------
// bf16 MFMA GEMM, DOUBLE-BUFFERED (best measured: 94.5-96.7us, ~720 TF):
// next k-tile's global_load_lds issues BEFORE the current tile's
// ds_read+MFMA, one __syncthreads() per k-tile. Two named buffer pairs.
// 128x128 tile, BK=64, 4 waves, XCD-aware remap, XOR-swizzled LDS
// (pre-swizzled global source, same XOR on read), fused chunk-carry
// epilogue. Schedule attempts that LOST to this: counted-vmcnt 4-phase
// 256^2 (R6: 107us), 128x512 wide-tile reg-staged A (R5: 174us),
// fp32-A fused-cast variants (R2/R3: 179us), full scan fusion (R7/R8:
// 167/177us vs this pipeline's gemm+apply = ~130us).
// ---------------------------------------------------------------------------
#define STAGE_TILE(AsD, BsD, k0)                                          \
  {                                                                       \
    _Pragma("unroll")                                                     \
    for (int q = 0; q < 4; ++q) {                                         \
      int slot = q * 256 + tid;                                           \
      int row  = slot >> 3;                                               \
      int ch   = slot & 7;                                                \
      int sc   = ch ^ (row & 7);                                          \
      async_load16(Ag + (size_t)(bm0 + row) * K_DIM + (k0) + sc * 8,      \
                   &AsD[(q * 256 + wid * 64) * 8]);                       \
    }                                                                     \
    _Pragma("unroll")                                                     \
    for (int q = 0; q < 4; ++q) {                                         \
      int slot = q * 256 + tid;                                           \
      int row  = slot >> 3;                                               \
      int ch   = slot & 7;                                                \
      int sc   = ch ^ (row & 7);                                          \
      async_load16(Bg + (size_t)(bn0 + row) * K_DIM + (k0) + sc * 8,      \
                   &BsD[(q * 256 + wid * 64) * 8]);                       \
    }                                                                     \
  }

#define COMPUTE_TILE(AsS, BsS)                                            \
  {                                                                       \
    _Pragma("unroll")                                                     \
    for (int ks = 0; ks < 2; ++ks) {                                      \
      short8 af[4], bfr[4];                                               \
      _Pragma("unroll")                                                   \
      for (int i = 0; i < 4; ++i) {                                       \
        int r = wm * 64 + i * 16 + l15;                                   \
        int c = ks * 4 + quad;                                            \
        af[i] = *(const short8*)&AsS[r * 64 + ((c ^ (r & 7)) * 8)];       \
      }                                                                   \
      _Pragma("unroll")                                                   \
      for (int j = 0; j < 4; ++j) {                                       \
        int r = wn * 64 + j * 16 + l15;                                   \
        int c = ks * 4 + quad;                                            \
        bfr[j] = *(const short8*)&BsS[r * 64 + ((c ^ (r & 7)) * 8)];      \
      }                                                                   \
      _Pragma("unroll")                                                   \
      for (int i = 0; i < 4; ++i)                                         \
        _Pragma("unroll")                                                 \
        for (int j = 0; j < 4; ++j)                                       \
          acc[i][j] = __builtin_amdgcn_mfma_f32_16x16x32_bf16(            \
              af[i], bfr[j], acc[i][j], 0, 0, 0);                         \
    }                                                                     \
  }

__global__ __launch_bounds__(256) void gemm_mfma_db(
    const unsigned short* __restrict__ Ag,  // [M, K] bf16
    const unsigned short* __restrict__ Bg,  // [N, K] bf16
    const float* __restrict__ bias,         // [N]
    const float* __restrict__ decay,        // [N]
    unsigned short* outBf,                  // [M, N] bf16 (or null)
    float* outF,                            // [M, N] fp32 (or null)
    float* carry) {                         // [B, NCHUNK, N] (or null)
    __shared__ unsigned short As0[128 * 64];
    __shared__ unsigned short Bs0[128 * 64];
    __shared__ unsigned short As1[128 * 64];
    __shared__ unsigned short Bs1[128 * 64];

    const int tid  = threadIdx.x;
    const int lane = tid & 63;
    const int wid  = tid >> 6;
    const int l15  = lane & 15;
    const int quad = lane >> 4;
    const int wm   = wid >> 1;
    const int wn   = wid & 1;

    // XCD-aware remap (grid is (8, 256) -> L in [0, 2048))
    const int L    = blockIdx.y * gridDim.x + blockIdx.x;
    const int xcd  = L & 7;
    const int s    = L >> 3;
    const int bn0  = (s & 7) * 128;                 // N-tile
    const int bm0  = (xcd * 32 + (s >> 3)) * 128;   // M-panel

    floatx4 acc[4][4];
#pragma unroll
    for (int i = 0; i < 4; ++i)
#pragma unroll
        for (int j = 0; j < 4; ++j)
            acc[i][j] = (floatx4){0.f, 0.f, 0.f, 0.f};

    // Prologue: stage tile 0 into buffer 0.
    STAGE_TILE(As0, Bs0, 0);
    __syncthreads();

    // 16 k-tiles, processed 2 per unrolled iteration (ping/pong).
#pragma unroll 1
    for (int kt = 0; kt < K_DIM / 64; kt += 2) {
        STAGE_TILE(As1, Bs1, (kt + 1) * 64);    // in flight during compute
        COMPUTE_TILE(As0, Bs0);
        __syncthreads();                        // drains vmcnt + syncs buf0 reuse
        if (kt + 2 < K_DIM / 64)
            STAGE_TILE(As0, Bs0, (kt + 2) * 64);
        COMPUTE_TILE(As1, Bs1);
        __syncthreads();
    }

    // C/D layout: col = lane&15, row = quad*4 + reg
#pragma unroll
    for (int j = 0; j < 4; ++j) {
        int col = bn0 + wn * 64 + j * 16 + l15;
        float bb = bias[col];
#pragma unroll
        for (int i = 0; i < 4; ++i) {
            int rowb = bm0 + wm * 64 + i * 16 + quad * 4;
#pragma unroll
            for (int r = 0; r < 4; ++r) {
                float v = acc[i][j][r] + bb;
                size_t idx = (size_t)(rowb + r) * N_DIM + col;
                if (outBf) outBf[idx] = f2bf(v);
                else       outF[idx]  = v;
            }
        }
    }

    // ---- fused chunk-carry epilogue (harness-verified R1/R4/R9) ----
    // U = (1-a)*sum_{rloc} a^(63-rloc)*acc + bias*(1-a^64), rloc = i*16+quad*4+r
    if (carry) {
        const int bIdx = bm0 >> 10;                       // / T_DIM
        const int g    = ((bm0 & (T_DIM - 1)) >> 6) + wm; // chunk index
#pragma unroll
        for (int j = 0; j < 4; ++j) {
            int col = bn0 + wn * 64 + j * 16 + l15;
            float a   = decay[col];
            float bb  = bias[col];
            float a2  = a * a;
            float a4  = a2 * a2;
            float a8  = a4 * a4;
            float a12 = a8 * a4;
            float a64 = a12 * a4;          // a^16
            a64 = a64 * a64;               // a^32
            a64 = a64 * a64;               // a^64
            float w = (quad == 0) ? a12 : (quad == 1) ? a8
                    : (quad == 2) ? a4  : 1.0f;
            float sacc = 0.f;
#pragma unroll
            for (int i = 3; i >= 0; --i) {
#pragma unroll
                for (int r = 3; r >= 0; --r) {
                    sacc += w * acc[i][j][r];
                    w *= a;
                }
                if (i) w *= a12;           // row gap 13 across fragments
            }
            sacc += __shfl_xor(sacc, 16);
            sacc += __shfl_xor(sacc, 32);
            float U = (1.0f - a) * sacc + bb * (1.0f - a64);
            if (quad == 0)
                carry[((size_t)bIdx * NCHUNK + g) * N_DIM + col] = U;
        }
    }
}

// ---------------------------------------------------------------------------
// Apply pass, 4-wide over o: uint2 loads (8B/lane), float4 stores (16B/lane).
// Thread <-> (b, chunk, o4): o4 = tid&255, chunk = (tid>>8)&15, b = tid>>12.
// 131072 threads = 2048 waves = 8 waves/CU; 32-deep load pipeline. ~33us,
// at its ~31us BW floor (194 MB).
// ---------------------------------------------------------------------------
__global__ __launch_bounds__(256) void scan_apply4(
    const uint2* __restrict__ cur4,           // [M, N/4] (2x bf16-pair)
    const float* __restrict__ decay,
    const float* __restrict__ carry,          // [B, NCHUNK, N]
    float* __restrict__ out) {                // [M, N] fp32
    int tid   = blockIdx.x * 256 + threadIdx.x;   // 0 .. 131071
    int o4    = tid & 255;
    int chunk = (tid >> 8) & (NCHUNK - 1);
    int b     = tid >> 12;
    int o     = o4 * 4;
    size_t base = ((size_t)b * T_DIM + (size_t)chunk * CHUNK_T) * (N_DIM / 4) + o4;
    float4 av = *(const float4*)&decay[o];
    float a0 = av.x, a1 = av.y, a2 = av.z, a3 = av.w;
    float c0 = 1.f - a0, c1 = 1.f - a1, c2 = 1.f - a2, c3 = 1.f - a3;

    float A0 = a0, A1 = a1, A2 = a2, A3 = a3;
#pragma unroll
    for (int i = 0; i < 6; ++i) { A0 *= A0; A1 *= A1; A2 *= A2; A3 *= A3; }  // a^64

    float u0 = 0.f, u1 = 0.f, u2 = 0.f, u3 = 0.f;
    const float* cb = carry + (size_t)b * NCHUNK * N_DIM + o;
    for (int i = 0; i < chunk; ++i) {         // wave-uniform trip count
        float4 cv = *(const float4*)&cb[(size_t)i * N_DIM];
        u0 = cv.x + A0 * u0;
        u1 = cv.y + A1 * u1;
        u2 = cv.z + A2 * u2;
        u3 = cv.w + A3 * u3;
    }

    float4* out4 = (float4*)out;
    for (int t0 = 0; t0 < CHUNK_T; t0 += 32) {
        uint2 x[32];
#pragma unroll
        for (int k = 0; k < 32; ++k)
            x[k] = cur4[base + (size_t)(t0 + k) * (N_DIM / 4)];
#pragma unroll
        for (int k = 0; k < 32; ++k) {
            float v0 = __uint_as_float(x[k].x << 16);
            float v1 = __uint_as_float(x[k].x & 0xffff0000u);
            float v2 = __uint_as_float(x[k].y << 16);
            float v3 = __uint_as_float(x[k].y & 0xffff0000u);
            u0 = a0 * u0 + c0 * v0;
            u1 = a1 * u1 + c1 * v1;
            u2 = a2 * u2 + c2 * v2;
            u3 = a3 * u3 + c3 * v3;
            out4[base + (size_t)(t0 + k) * (N_DIM / 4)] = (float4){u0, u1, u2, u3};
        }
    }
}

// ---------------------------------------------------------------------------
// Fallbacks (only used if workspace too small for the bf16 path)
// ---------------------------------------------------------------------------
__global__ void scan_f32_inplace(float* __restrict__ buf,
                                 const float* __restrict__ decay) {
    int tid = blockIdx.x * 64 + threadIdx.x;
    int o = tid & (N_DIM - 1);
    size_t base = ((size_t)(tid >> 10) << 20) + o;
    float a = decay[o];
    float c = 1.f - a;
    float u = 0.f;
    for (int t0 = 0; t0 < 1024; t0 += 16) {
        float x[16];
#pragma unroll
        for (int k = 0; k < 16; ++k)
            x[k] = buf[base + (size_t)(t0 + k) * N_DIM];
#pragma unroll
        for (int k = 0; k < 16; ++k) {
            u = a * u + c * x[k];
            buf[base + (size_t)(t0 + k) * N_DIM] = u;
        }
    }
}

__global__ void gemm_naive(const float* __restrict__ X, const float* __restrict__ W,
                           const float* __restrict__ bias, float* __restrict__ out) {
    __shared__ float As[16][17], Bs[16][17];
    int tx = threadIdx.x, ty = threadIdx.y;
    int m0 = blockIdx.y * 16, n0 = blockIdx.x * 16;
    float acc = 0.f;
    for (int k0 = 0; k0 < K_DIM; k0 += 16) {
        As[ty][tx] = X[(size_t)(m0 + ty) * K_DIM + k0 + tx];
        Bs[ty][tx] = W[(size_t)(n0 + ty) * K_DIM + k0 + tx];
        __syncthreads();
#pragma unroll
        for (int kk = 0; kk < 16; ++kk) acc += As[ty][kk] * Bs[tx][kk];
        __syncthreads();
    }
    out[(size_t)(m0 + ty) * N_DIM + n0 + tx] = acc + bias[n0 + tx];
}

// ---------------------------------------------------------------------------
extern "C" void kernel_launch(void* const* d_in, const int* in_sizes, int n_in,
                              void* d_out, int out_size, void* d_ws, size_t ws_size,
                              hipStream_t stream) {
    const float* X     = (const float*)d_in[0];  // [B,T,IN]  = [M,K]
    const float* Wt    = (const float*)d_in[1];  // [OUT,IN]  = [N,K]
    const float* bias  = (const float*)d_in[2];  // [OUT]
    const float* decay = (const float*)d_in[3];  // [OUT]
    float* out = (float*)d_out;                  // [B,T,OUT] = [M,N]

    const size_t A_bytes  = (size_t)M_DIM * K_DIM * 2;            // 64 MB
    const size_t W_bytes  = (size_t)N_DIM * K_DIM * 2;            // 2 MB
    const size_t C_bytes  = (size_t)M_DIM * N_DIM * 2;            // 64 MB
    const size_t cr_bytes = (size_t)B_DIM * NCHUNK * N_DIM * 4;   // 2 MB
    const size_t need_mid  = A_bytes + W_bytes;
    const size_t need_full = A_bytes + W_bytes + C_bytes + cr_bytes;

    const int nA8   = M_DIM * K_DIM / 8;
    const int nW8   = N_DIM * K_DIM / 8;
    const int nTot8 = nA8 + nW8;

    if (ws_size >= need_full) {
        unsigned short* Abf = (unsigned short*)d_ws;
        unsigned short* Wbf = (unsigned short*)((char*)d_ws + A_bytes);
        unsigned short* Cbf = (unsigned short*)((char*)d_ws + A_bytes + W_bytes);
        float* carry = (float*)((char*)d_ws + A_bytes + W_bytes + C_bytes);
        cast_f32_bf16_fused<<<(nTot8 + 255) / 256, 256, 0, stream>>>(X, Wt, Abf, nA8, nTot8);
        gemm_mfma_db<<<dim3(N_DIM / 128, M_DIM / 128), 256, 0, stream>>>(
            Abf, Wbf, bias, decay, Cbf, nullptr, carry);
        const int apply_threads = B_DIM * NCHUNK * N_DIM / 4;     // 131072
        scan_apply4<<<apply_threads / 256, 256, 0, stream>>>(
            (const uint2*)Cbf, decay, carry, out);
    } else if (ws_size >= need_mid) {
        unsigned short* Abf = (unsigned short*)d_ws;
        unsigned short* Wbf = (unsigned short*)((char*)d_ws + A_bytes);
        cast_f32_bf16_fused<<<(nTot8 + 255) / 256, 256, 0, stream>>>(X, Wt, Abf, nA8, nTot8);
        gemm_mfma_db<<<dim3(N_DIM / 128, M_DIM / 128), 256, 0, stream>>>(
            Abf, Wbf, bias, decay, nullptr, out, nullptr);
        scan_f32_inplace<<<512, 64, 0, stream>>>(out, decay);
    } else {
        gemm_naive<<<dim3(N_DIM / 16, M_DIM / 16), dim3(16, 16), 0, stream>>>(X, Wt, bias, out);
        scan_f32_inplace<<<512, 64, 0, stream>>>(out, decay);
    }
}